// Round 9
// baseline (93.733 us; speedup 1.0000x reference)
//
#include <hip/hip_runtime.h>
#include <hip/hip_fp16.h>
#include <math.h>

#define BB 16
#define NN 1024
#define DD 768
#define KK 8
#define BETA_F 0.5f
#define EPS_F 1e-8f

#define TPK_BLOCKS ((BB * NN) / 4)         // 4096: one wave per point, 4 points/block
#define NORM_BLOCKS ((BB * NN) / 4)        // 4096

typedef _Float16 h2_t __attribute__((ext_vector_type(2)));

#if defined(__has_builtin)
#if __has_builtin(__builtin_amdgcn_fdot2)
#define HAVE_FDOT2 1
#endif
#endif

// acc += dot of 4 halves packed in uint2 (v_dot2_f32_f16 x2, or unpack-fma fallback)
__device__ __forceinline__ float dot4acc(uint2 a, uint2 b, float acc) {
#ifdef HAVE_FDOT2
    acc = __builtin_amdgcn_fdot2(__builtin_bit_cast(h2_t, a.x),
                                 __builtin_bit_cast(h2_t, b.x), acc, false);
    acc = __builtin_amdgcn_fdot2(__builtin_bit_cast(h2_t, a.y),
                                 __builtin_bit_cast(h2_t, b.y), acc, false);
#else
    float2 fa = __half22float2(__builtin_bit_cast(__half2, a.x));
    float2 fb = __half22float2(__builtin_bit_cast(__half2, b.x));
    acc = fmaf(fa.x, fb.x, acc); acc = fmaf(fa.y, fb.y, acc);
    fa = __half22float2(__builtin_bit_cast(__half2, a.y));
    fb = __half22float2(__builtin_bit_cast(__half2, b.y));
    acc = fmaf(fa.x, fb.x, acc); acc = fmaf(fa.y, fb.y, acc);
#endif
    return acc;
}

// ---------------------------------------------------------------------------
// Wave-wide f64 min via DPP (VALU pipe, no LDS): row_shr 1/2/4/8 accumulate a
// running min so lane 15 of each 16-row holds the row min; row_bcast:15
// (rows 1,3) and row_bcast:31 (rows 2,3) fold rows so lane 63 holds the full
// 64-lane min; readlane broadcasts it. min over distinct finite keys is
// order-independent -> bit-identical to the shfl_xor butterfly it replaces.
// ---------------------------------------------------------------------------
__device__ __forceinline__ double wave_min_f64_to_all(double x) {
#define DPPMIN(CTRL, RM) {                                                  \
        uint2 u_ = __builtin_bit_cast(uint2, x);                            \
        uint2 y_;                                                           \
        y_.x = (unsigned)__builtin_amdgcn_update_dpp((int)u_.x, (int)u_.x,  \
                                                     CTRL, RM, 0xf, false); \
        y_.y = (unsigned)__builtin_amdgcn_update_dpp((int)u_.y, (int)u_.y,  \
                                                     CTRL, RM, 0xf, false); \
        x = fmin(x, __builtin_bit_cast(double, y_));                        \
    }
    DPPMIN(0x111, 0xf)   // row_shr:1
    DPPMIN(0x112, 0xf)   // row_shr:2
    DPPMIN(0x114, 0xf)   // row_shr:4
    DPPMIN(0x118, 0xf)   // row_shr:8
    DPPMIN(0x142, 0xa)   // row_bcast:15 -> rows 1,3
    DPPMIN(0x143, 0xc)   // row_bcast:31 -> rows 2,3
#undef DPPMIN
    uint2 u = __builtin_bit_cast(uint2, x);
    uint2 r;
    r.x = (unsigned)__builtin_amdgcn_readlane((int)u.x, 63);
    r.y = (unsigned)__builtin_amdgcn_readlane((int)u.y, 63);
    return __builtin_bit_cast(double, r);
}

// ---------------------------------------------------------------------------
// topk: exact top-9 NN per point, wave-wide 9-round min extraction (flat
// kill+rebuild structure of round 7, proven bit-exact; only the cross-lane
// reduce switched from shfl_xor/LDS to DPP/VALU).
// Key = (double)u * 1024 + m (exact integer < 2^42).
// ---------------------------------------------------------------------------
__device__ __forceinline__ unsigned topk_u(float anx, float any_, float sqn, float4 c) {
    float dot = anx * c.x + any_ * c.y;
    float d2  = (sqn + c.z) - 2.0f * dot;
    unsigned int u = __float_as_uint(d2);
    u ^= (unsigned int)((int)u >> 31) | 0x80000000u;
    return u;
}

#define KINF 1.0e300

#define K16(X) X(0) X(1) X(2) X(3) X(4) X(5) X(6) X(7) \
               X(8) X(9) X(10) X(11) X(12) X(13) X(14) X(15)

#define MINTREE() fmin(fmin(fmin(fmin(k0,k1),fmin(k2,k3)),                 \
                            fmin(fmin(k4,k5),fmin(k6,k7))),               \
                       fmin(fmin(fmin(k8,k9),fmin(k10,k11)),              \
                            fmin(fmin(k12,k13),fmin(k14,k15))))

__device__ __forceinline__ void topk_wave_body(const float* __restrict__ centers,
                                               int* __restrict__ idx_out,
                                               int tb, int tid, float4* c4) {
    const int b    = tb >> 8;          // 256 blocks per batch
    const int grp  = tb & 255;
    const int wave = tid >> 6;
    const int lane = tid & 63;

    // stage packed (x, y, x^2+y^2) — identical arithmetic to prior rounds
    const float4* cbase = (const float4*)(centers + (size_t)b * NN * 2);
    for (int i = tid; i < NN / 2; i += 256) {
        float4 v = cbase[i];
        c4[2 * i + 0] = make_float4(v.x, v.y, v.x * v.x + v.y * v.y, 0.f);
        c4[2 * i + 1] = make_float4(v.z, v.w, v.z * v.z + v.w * v.w, 0.f);
    }
    __syncthreads();

    const int    n   = grp * 4 + wave;   // point within batch
    const float4 cn  = c4[n];
    const float  anx = cn.x, any_ = cn.y, sqn = cn.z;

#define DK(i) double k##i;
    K16(DK)
#undef DK
#define IK(i) { const int m_ = (i) * 64 + lane;                            \
                float4 c_ = c4[m_];                                        \
                unsigned u_ = topk_u(anx, any_, sqn, c_);                  \
                k##i = fma((double)u_, 1024.0, (double)m_); }
    K16(IK)
#undef IK

    double lm = MINTREE();
    int mm[9];

#define VK(i) k##i = (k##i == g) ? KINF : k##i;
#define TOPK_ROUND(r) {                                                    \
        const double g = wave_min_f64_to_all(lm);                          \
        double qf = floor(g * 0.0009765625) * 1024.0;                      \
        mm[r] = (int)(g - qf);                                             \
        K16(VK)                                                            \
        lm = MINTREE();                                                    \
    }
    TOPK_ROUND(0)   // global min (self or negative-rounded pair) — dropped
    TOPK_ROUND(1)
    TOPK_ROUND(2)
    TOPK_ROUND(3)
    TOPK_ROUND(4)
    TOPK_ROUND(5)
    TOPK_ROUND(6)
    TOPK_ROUND(7)
    TOPK_ROUND(8)
#undef TOPK_ROUND
#undef VK

    if (lane == 0) {
        int* outp = idx_out + ((size_t)b * NN + n) * KK;
        ((int4*)outp)[0] = make_int4(mm[1], mm[2], mm[3], mm[4]);
        ((int4*)outp)[1] = make_int4(mm[5], mm[6], mm[7], mm[8]);
    }
}

// ---------------------------------------------------------------------------
// normh body: row-normalize s,t in fp32, emit normalized fp16. One wave/row.
// (unchanged from rounds 6-8)
// ---------------------------------------------------------------------------
__device__ __forceinline__ void normh_body(const float* __restrict__ s,
                                           const float* __restrict__ t,
                                           __half* __restrict__ ns,
                                           __half* __restrict__ nt,
                                           int nb, int tid) {
    const int row  = nb * 4 + (tid >> 6);
    const int lane = tid & 63;
    const float4* srow = (const float4*)(s + (size_t)row * DD);
    const float4* trow = (const float4*)(t + (size_t)row * DD);
    float4 vs[3], vt[3];
    float ss = 0.f, tt = 0.f;
#pragma unroll
    for (int i = 0; i < 3; ++i) {
        vs[i] = srow[lane + 64 * i];
        vt[i] = trow[lane + 64 * i];
        ss = fmaf(vs[i].x, vs[i].x, fmaf(vs[i].y, vs[i].y,
             fmaf(vs[i].z, vs[i].z, fmaf(vs[i].w, vs[i].w, ss))));
        tt = fmaf(vt[i].x, vt[i].x, fmaf(vt[i].y, vt[i].y,
             fmaf(vt[i].z, vt[i].z, fmaf(vt[i].w, vt[i].w, tt))));
    }
#pragma unroll
    for (int m = 1; m < 64; m <<= 1) {
        ss += __shfl_xor(ss, m);
        tt += __shfl_xor(tt, m);
    }
    const float is_ = 1.0f / fmaxf(sqrtf(ss), EPS_F);
    const float it_ = 1.0f / fmaxf(sqrtf(tt), EPS_F);

    uint2* nsrow = (uint2*)(ns + (size_t)row * DD);
    uint2* ntrow = (uint2*)(nt + (size_t)row * DD);
#pragma unroll
    for (int i = 0; i < 3; ++i) {
        __half2 a0 = __floats2half2_rn(vs[i].x * is_, vs[i].y * is_);
        __half2 a1 = __floats2half2_rn(vs[i].z * is_, vs[i].w * is_);
        __half2 b0 = __floats2half2_rn(vt[i].x * it_, vt[i].y * it_);
        __half2 b1 = __floats2half2_rn(vt[i].z * it_, vt[i].w * it_);
        uint2 ua; ua.x = __builtin_bit_cast(unsigned int, a0);
        ua.y = __builtin_bit_cast(unsigned int, a1);
        uint2 ub; ub.x = __builtin_bit_cast(unsigned int, b0);
        ub.y = __builtin_bit_cast(unsigned int, b1);
        nsrow[lane + 64 * i] = ua;
        ntrow[lane + 64 * i] = ub;
    }
}

// ---------------------------------------------------------------------------
// Fused kernel: roles interleaved on blockIdx&1 so every CU overlaps the
// VALU-bound topk with the HBM-bound normh from t=0. LDS 16 KB.
// launch_bounds(256,4): cap 128 VGPR so the 16 f64 keys stay in VGPRs while
// keeping >=4 blocks/CU for the streaming half.
// ---------------------------------------------------------------------------
__global__ __launch_bounds__(256, 4) void fused_prep(const float* __restrict__ centers,
                                                     const float* __restrict__ s,
                                                     const float* __restrict__ t,
                                                     int* __restrict__ idx_out,
                                                     __half* __restrict__ ns,
                                                     __half* __restrict__ nt) {
    __shared__ float4 c4[NN];                 // 16 KB
    const int role = blockIdx.x & 1;
    const int tb   = blockIdx.x >> 1;
    if (role == 0)
        topk_wave_body(centers, idx_out, tb, threadIdx.x, c4);
    else
        normh_body(s, t, ns, nt, tb, threadIdx.x);
}

// standalone topk for the f32 fallback path
__global__ __launch_bounds__(256, 4) void topk_kernel(const float* __restrict__ centers,
                                                      int* __restrict__ idx_out) {
    __shared__ float4 c4[NN];
    topk_wave_body(centers, idx_out, blockIdx.x, threadIdx.x, c4);
}

// ---------------------------------------------------------------------------
// lossh: gather normalized fp16 rows, dot -> cosines, smooth-L1, per-block
// partial. XCD batch-affinity swizzle. (unchanged from rounds 6-8)
// ---------------------------------------------------------------------------
__global__ __launch_bounds__(256) void lossh_kernel(const __half* __restrict__ ns,
                                                    const __half* __restrict__ nt,
                                                    const int* __restrict__ idx,
                                                    float* __restrict__ part) {
    const int bid  = blockIdx.x;
    const int v    = (bid & 7) * 512 + (bid >> 3);   // bijective, nwg%8==0
    const int wave = threadIdx.x >> 6;
    const int lane = threadIdx.x & 63;
    const int p    = v * 4 + wave;
    const int base = p & ~(NN - 1);

    int q[8];
    {
        const int4* ip = (const int4*)(idx + (size_t)p * KK);
        int4 a = ip[0], c = ip[1];
        q[0] = base + a.x; q[1] = base + a.y; q[2] = base + a.z; q[3] = base + a.w;
        q[4] = base + c.x; q[5] = base + c.y; q[6] = base + c.z; q[7] = base + c.w;
    }

    const uint2* srow = (const uint2*)(ns + (size_t)p * DD);
    const uint2* trow = (const uint2*)(nt + (size_t)p * DD);
    uint2 sa[3], ta[3];
#pragma unroll
    for (int c = 0; c < 3; ++c) {
        sa[c] = srow[lane + 64 * c];
        ta[c] = trow[lane + 64 * c];
    }

    uint2 sv[8][3], tv[8][3];
#pragma unroll
    for (int j = 0; j < 8; ++j) {
        const uint2* snb = (const uint2*)(ns + (size_t)q[j] * DD);
        const uint2* tnb = (const uint2*)(nt + (size_t)q[j] * DD);
#pragma unroll
        for (int c = 0; c < 3; ++c) {
            sv[j][c] = snb[lane + 64 * c];
            tv[j][c] = tnb[lane + 64 * c];
        }
    }

    float ds[8], dt[8];
#pragma unroll
    for (int j = 0; j < 8; ++j) {
        float a = 0.f, b = 0.f;
#pragma unroll
        for (int c = 0; c < 3; ++c) {
            a = dot4acc(sa[c], sv[j][c], a);
            b = dot4acc(ta[c], tv[j][c], b);
        }
        ds[j] = a;
        dt[j] = b;
    }
#pragma unroll
    for (int m = 1; m < 64; m <<= 1) {
#pragma unroll
        for (int j = 0; j < 8; ++j) {
            ds[j] += __shfl_xor(ds[j], m);
            dt[j] += __shfl_xor(dt[j], m);
        }
    }
    float sum = 0.f;
#pragma unroll
    for (int j = 0; j < 8; ++j) {
        const float diff = fabsf(ds[j] - dt[j]);     // rows pre-normalized
        sum += diff < BETA_F ? (0.5f * diff * diff / BETA_F) : (diff - 0.5f * BETA_F);
    }

    __shared__ float wpart[4];
    if (lane == 0) wpart[wave] = sum;
    __syncthreads();
    if (threadIdx.x == 0)
        part[v] = (wpart[0] + wpart[1]) + (wpart[2] + wpart[3]);
}

// ---------------------------------------------------------------------------
// f32 fallback path (only if ws_size too small for fp16 copies).
// ---------------------------------------------------------------------------
__global__ __launch_bounds__(256) void norm_kernel(const float* __restrict__ s,
                                                   const float* __restrict__ t,
                                                   float* __restrict__ inv_s,
                                                   float* __restrict__ inv_t) {
    const int row  = blockIdx.x * 4 + (threadIdx.x >> 6);
    const int lane = threadIdx.x & 63;
    const float4* srow = (const float4*)(s + (size_t)row * DD);
    const float4* trow = (const float4*)(t + (size_t)row * DD);
    float ss = 0.f, tt = 0.f;
#pragma unroll
    for (int i = 0; i < 3; ++i) {
        float4 v = srow[lane + 64 * i];
        ss = fmaf(v.x, v.x, fmaf(v.y, v.y, fmaf(v.z, v.z, fmaf(v.w, v.w, ss))));
        float4 w = trow[lane + 64 * i];
        tt = fmaf(w.x, w.x, fmaf(w.y, w.y, fmaf(w.z, w.z, fmaf(w.w, w.w, tt))));
    }
#pragma unroll
    for (int m = 1; m < 64; m <<= 1) {
        ss += __shfl_xor(ss, m);
        tt += __shfl_xor(tt, m);
    }
    if (lane == 0) {
        inv_s[row] = 1.0f / fmaxf(sqrtf(ss), EPS_F);
        inv_t[row] = 1.0f / fmaxf(sqrtf(tt), EPS_F);
    }
}

__global__ __launch_bounds__(256) void lossf_kernel(const float* __restrict__ s,
                                                    const float* __restrict__ t,
                                                    const int* __restrict__ idx,
                                                    const float* __restrict__ inv_s,
                                                    const float* __restrict__ inv_t,
                                                    float* __restrict__ part) {
    const int wave = threadIdx.x >> 6;
    const int lane = threadIdx.x & 63;
    const int p    = blockIdx.x * 4 + wave;
    const int base = p & ~(NN - 1);
    int q[8];
    {
        const int4* ip = (const int4*)(idx + (size_t)p * KK);
        int4 a = ip[0], c = ip[1];
        q[0] = base + a.x; q[1] = base + a.y; q[2] = base + a.z; q[3] = base + a.w;
        q[4] = base + c.x; q[5] = base + c.y; q[6] = base + c.z; q[7] = base + c.w;
    }
    float isq[8], itq[8];
#pragma unroll
    for (int j = 0; j < 8; ++j) { isq[j] = inv_s[q[j]]; itq[j] = inv_t[q[j]]; }
    const float isn = inv_s[p];
    const float itn = inv_t[p];
    const float4* srow = (const float4*)(s + (size_t)p * DD);
    const float4* trow = (const float4*)(t + (size_t)p * DD);
    float4 as0 = srow[lane], as1 = srow[lane + 64], as2 = srow[lane + 128];
    float4 at0 = trow[lane], at1 = trow[lane + 64], at2 = trow[lane + 128];
    float ds[8], dt[8];
#pragma unroll
    for (int j = 0; j < 8; ++j) {
        const float4* snb = (const float4*)(s + (size_t)q[j] * DD);
        const float4* tnb = (const float4*)(t + (size_t)q[j] * DD);
        float4 v0 = snb[lane], v1 = snb[lane + 64], v2 = snb[lane + 128];
        float4 w0 = tnb[lane], w1 = tnb[lane + 64], w2 = tnb[lane + 128];
        float a = 0.f, b = 0.f;
        a = fmaf(as0.x, v0.x, a); a = fmaf(as0.y, v0.y, a);
        a = fmaf(as0.z, v0.z, a); a = fmaf(as0.w, v0.w, a);
        a = fmaf(as1.x, v1.x, a); a = fmaf(as1.y, v1.y, a);
        a = fmaf(as1.z, v1.z, a); a = fmaf(as1.w, v1.w, a);
        a = fmaf(as2.x, v2.x, a); a = fmaf(as2.y, v2.y, a);
        a = fmaf(as2.z, v2.z, a); a = fmaf(as2.w, v2.w, a);
        b = fmaf(at0.x, w0.x, b); b = fmaf(at0.y, w0.y, b);
        b = fmaf(at0.z, w0.z, b); b = fmaf(at0.w, w0.w, b);
        b = fmaf(at1.x, w1.x, b); b = fmaf(at1.y, w1.y, b);
        b = fmaf(at1.z, w1.z, b); b = fmaf(at1.w, w1.w, b);
        b = fmaf(at2.x, w2.x, b); b = fmaf(at2.y, w2.y, b);
        b = fmaf(at2.z, w2.z, b); b = fmaf(at2.w, w2.w, b);
        ds[j] = a; dt[j] = b;
    }
#pragma unroll
    for (int m = 1; m < 64; m <<= 1) {
#pragma unroll
        for (int j = 0; j < 8; ++j) {
            ds[j] += __shfl_xor(ds[j], m);
            dt[j] += __shfl_xor(dt[j], m);
        }
    }
    float sum = 0.f;
#pragma unroll
    for (int j = 0; j < 8; ++j) {
        const float cs   = ds[j] * isn * isq[j];
        const float ct   = dt[j] * itn * itq[j];
        const float diff = fabsf(cs - ct);
        sum += diff < BETA_F ? (0.5f * diff * diff / BETA_F) : (diff - 0.5f * BETA_F);
    }
    __shared__ float wpart[4];
    if (lane == 0) wpart[wave] = sum;
    __syncthreads();
    if (threadIdx.x == 0)
        part[blockIdx.x] = (wpart[0] + wpart[1]) + (wpart[2] + wpart[3]);
}

// ---------------------------------------------------------------------------
// finalize: deterministic tree reduce of 4096 block partials + final scale.
// ---------------------------------------------------------------------------
__global__ __launch_bounds__(256) void finalize_kernel(const float* __restrict__ part,
                                                       float* __restrict__ out) {
    __shared__ float red[256];
    float acc = 0.f;
    for (int i = threadIdx.x; i < (BB * NN) / 4; i += 256) acc += part[i];
    red[threadIdx.x] = acc;
    __syncthreads();
    for (int off = 128; off > 0; off >>= 1) {
        if (threadIdx.x < off) red[threadIdx.x] += red[threadIdx.x + off];
        __syncthreads();
    }
    if (threadIdx.x == 0) out[0] = red[0] * (1.0f / (float)(BB * NN * KK));
}

extern "C" void kernel_launch(void* const* d_in, const int* in_sizes, int n_in,
                              void* d_out, int out_size, void* d_ws, size_t ws_size,
                              hipStream_t stream) {
    const float* student = (const float*)d_in[0];
    const float* teacher = (const float*)d_in[1];
    const float* centers = (const float*)d_in[2];
    float* out = (float*)d_out;

    const size_t idx_bytes  = (size_t)BB * NN * KK * sizeof(int);      // 512 KB
    const size_t half_bytes = (size_t)BB * NN * DD * sizeof(__half);   // 25.2 MB
    const size_t part_bytes = 4096 * sizeof(float);
    int* idx_buf = (int*)d_ws;

    if (ws_size >= idx_bytes + 2 * half_bytes + part_bytes) {
        __half* ns  = (__half*)((char*)d_ws + idx_bytes);
        __half* nt  = ns + (size_t)BB * NN * DD;
        float* part = (float*)((char*)d_ws + idx_bytes + 2 * half_bytes);
        fused_prep<<<TPK_BLOCKS + NORM_BLOCKS, 256, 0, stream>>>(centers, student,
                                                                 teacher, idx_buf, ns, nt);
        lossh_kernel<<<NORM_BLOCKS, 256, 0, stream>>>(ns, nt, idx_buf, part);
        finalize_kernel<<<1, 256, 0, stream>>>(part, out);
    } else {
        float* inv_s = (float*)((char*)d_ws + idx_bytes);
        float* inv_t = inv_s + BB * NN;
        float* part  = inv_t + BB * NN;
        topk_kernel<<<TPK_BLOCKS, 256, 0, stream>>>(centers, idx_buf);
        norm_kernel<<<NORM_BLOCKS, 256, 0, stream>>>(student, teacher, inv_s, inv_t);
        lossf_kernel<<<NORM_BLOCKS, 256, 0, stream>>>(student, teacher, idx_buf,
                                                      inv_s, inv_t, part);
        finalize_kernel<<<1, 256, 0, stream>>>(part, out);
    }
}

// Round 10
// 84.660 us; speedup vs baseline: 1.1072x; 1.1072x over previous
//
#include <hip/hip_runtime.h>
#include <hip/hip_fp16.h>
#include <math.h>

#define BB 16
#define NN 1024
#define DD 768
#define KK 8
#define BETA_F 0.5f
#define EPS_F 1e-8f

#define TPK_BLOCKS ((BB * NN) / 8)         // 2048: 4 waves/block x 2 points/wave
#define NORM_BLOCKS ((BB * NN) / 4)        // 4096

typedef _Float16 h2_t __attribute__((ext_vector_type(2)));

#if defined(__has_builtin)
#if __has_builtin(__builtin_amdgcn_fdot2)
#define HAVE_FDOT2 1
#endif
#endif

// acc += dot of 4 halves packed in uint2 (v_dot2_f32_f16 x2, or unpack-fma fallback)
__device__ __forceinline__ float dot4acc(uint2 a, uint2 b, float acc) {
#ifdef HAVE_FDOT2
    acc = __builtin_amdgcn_fdot2(__builtin_bit_cast(h2_t, a.x),
                                 __builtin_bit_cast(h2_t, b.x), acc, false);
    acc = __builtin_amdgcn_fdot2(__builtin_bit_cast(h2_t, a.y),
                                 __builtin_bit_cast(h2_t, b.y), acc, false);
#else
    float2 fa = __half22float2(__builtin_bit_cast(__half2, a.x));
    float2 fb = __half22float2(__builtin_bit_cast(__half2, b.x));
    acc = fmaf(fa.x, fb.x, acc); acc = fmaf(fa.y, fb.y, acc);
    fa = __half22float2(__builtin_bit_cast(__half2, a.y));
    fb = __half22float2(__builtin_bit_cast(__half2, b.y));
    acc = fmaf(fa.x, fb.x, acc); acc = fmaf(fa.y, fb.y, acc);
#endif
    return acc;
}

// ---------------------------------------------------------------------------
// Wave-wide f64 min via DPP (VALU pipe, no LDS) — unchanged from round 9
// (proven bit-exact). min over distinct finite keys is order-independent.
// ---------------------------------------------------------------------------
__device__ __forceinline__ double wave_min_f64_to_all(double x) {
#define DPPMIN(CTRL, RM) {                                                  \
        uint2 u_ = __builtin_bit_cast(uint2, x);                            \
        uint2 y_;                                                           \
        y_.x = (unsigned)__builtin_amdgcn_update_dpp((int)u_.x, (int)u_.x,  \
                                                     CTRL, RM, 0xf, false); \
        y_.y = (unsigned)__builtin_amdgcn_update_dpp((int)u_.y, (int)u_.y,  \
                                                     CTRL, RM, 0xf, false); \
        x = fmin(x, __builtin_bit_cast(double, y_));                        \
    }
    DPPMIN(0x111, 0xf)   // row_shr:1
    DPPMIN(0x112, 0xf)   // row_shr:2
    DPPMIN(0x114, 0xf)   // row_shr:4
    DPPMIN(0x118, 0xf)   // row_shr:8
    DPPMIN(0x142, 0xa)   // row_bcast:15 -> rows 1,3
    DPPMIN(0x143, 0xc)   // row_bcast:31 -> rows 2,3
#undef DPPMIN
    uint2 u = __builtin_bit_cast(uint2, x);
    uint2 r;
    r.x = (unsigned)__builtin_amdgcn_readlane((int)u.x, 63);
    r.y = (unsigned)__builtin_amdgcn_readlane((int)u.y, 63);
    return __builtin_bit_cast(double, r);
}

// ---------------------------------------------------------------------------
// topk: exact top-9 NN, wave-wide 9-round min extraction. Key = (double)u*1024
// + m (exact integer < 2^42; same arithmetic as rounds 6-9, proven bit-exact).
// NEW this round: TWO independent points per wave (kA/kB chains interleave ->
// 2x issue density per wave, half the waves) + keys pinned to arch VGPRs.
// ---------------------------------------------------------------------------
__device__ __forceinline__ unsigned topk_u(float anx, float any_, float sqn, float4 c) {
    float dot = anx * c.x + any_ * c.y;
    float d2  = (sqn + c.z) - 2.0f * dot;
    unsigned int u = __float_as_uint(d2);
    u ^= (unsigned int)((int)u >> 31) | 0x80000000u;
    return u;
}

#define KINF 1.0e300

struct Keys { double k[16]; };

// zero-cost: force the 16 key doubles to live in arch VGPRs ("v" class)
#define PIN_KEYS(K)                                                         \
    asm("" : "+v"(K.k[0]),  "+v"(K.k[1]),  "+v"(K.k[2]),  "+v"(K.k[3]),    \
             "+v"(K.k[4]),  "+v"(K.k[5]),  "+v"(K.k[6]),  "+v"(K.k[7]),    \
             "+v"(K.k[8]),  "+v"(K.k[9]),  "+v"(K.k[10]), "+v"(K.k[11]),   \
             "+v"(K.k[12]), "+v"(K.k[13]), "+v"(K.k[14]), "+v"(K.k[15]))

__device__ __forceinline__ void initkeys(Keys& K, float anx, float any_, float sqn,
                                         const float4* c4, int lane) {
#pragma unroll
    for (int i = 0; i < 16; ++i) {
        const int m_ = i * 64 + lane;
        float4 c_ = c4[m_];
        unsigned u_ = topk_u(anx, any_, sqn, c_);
        K.k[i] = fma((double)u_, 1024.0, (double)m_);
    }
}

__device__ __forceinline__ double mintree(const Keys& K) {
    return fmin(fmin(fmin(fmin(K.k[0], K.k[1]),  fmin(K.k[2], K.k[3])),
                     fmin(fmin(K.k[4], K.k[5]),  fmin(K.k[6], K.k[7]))),
                fmin(fmin(fmin(K.k[8], K.k[9]),  fmin(K.k[10], K.k[11])),
                     fmin(fmin(K.k[12], K.k[13]), fmin(K.k[14], K.k[15]))));
}

__device__ __forceinline__ void killkey(Keys& K, double g) {
#pragma unroll
    for (int i = 0; i < 16; ++i) K.k[i] = (K.k[i] == g) ? KINF : K.k[i];
}

__device__ __forceinline__ int decode_m(double g) {
    double qf = floor(g * 0.0009765625) * 1024.0;
    return (int)(g - qf);
}

__device__ __forceinline__ void topk_wave_body(const float* __restrict__ centers,
                                               int* __restrict__ idx_out,
                                               int tb, int tid, float4* c4) {
    const int b    = tb >> 7;          // 128 topk blocks per batch
    const int grp  = tb & 127;
    const int wave = tid >> 6;
    const int lane = tid & 63;

    // stage packed (x, y, x^2+y^2) — identical arithmetic to prior rounds
    const float4* cbase = (const float4*)(centers + (size_t)b * NN * 2);
    for (int i = tid; i < NN / 2; i += 256) {
        float4 v = cbase[i];
        c4[2 * i + 0] = make_float4(v.x, v.y, v.x * v.x + v.y * v.y, 0.f);
        c4[2 * i + 1] = make_float4(v.z, v.w, v.z * v.z + v.w * v.w, 0.f);
    }
    __syncthreads();

    const int nA = grp * 8 + wave * 2;   // two points per wave
    const int nB = nA + 1;
    const float4 cA = c4[nA];
    const float4 cB = c4[nB];

    Keys KA, KB;
    initkeys(KA, cA.x, cA.y, cA.z, c4, lane);
    initkeys(KB, cB.x, cB.y, cB.z, c4, lane);
    PIN_KEYS(KA);
    PIN_KEYS(KB);

    double lmA = mintree(KA);
    double lmB = mintree(KB);
    int mmA[9], mmB[9];

#pragma unroll
    for (int r = 0; r < 9; ++r) {
        const double gA = wave_min_f64_to_all(lmA);
        const double gB = wave_min_f64_to_all(lmB);
        mmA[r] = decode_m(gA);
        mmB[r] = decode_m(gB);
        killkey(KA, gA);
        killkey(KB, gB);
        PIN_KEYS(KA);
        PIN_KEYS(KB);
        lmA = mintree(KA);
        lmB = mintree(KB);
    }

    if (lane == 0) {
        int* outp = idx_out + ((size_t)b * NN + nA) * KK;   // nB rows follow
        ((int4*)outp)[0] = make_int4(mmA[1], mmA[2], mmA[3], mmA[4]);
        ((int4*)outp)[1] = make_int4(mmA[5], mmA[6], mmA[7], mmA[8]);
        ((int4*)outp)[2] = make_int4(mmB[1], mmB[2], mmB[3], mmB[4]);
        ((int4*)outp)[3] = make_int4(mmB[5], mmB[6], mmB[7], mmB[8]);
    }
}

// ---------------------------------------------------------------------------
// normh body: row-normalize s,t in fp32, emit normalized fp16. One wave/row.
// (unchanged from rounds 6-9)
// ---------------------------------------------------------------------------
__device__ __forceinline__ void normh_body(const float* __restrict__ s,
                                           const float* __restrict__ t,
                                           __half* __restrict__ ns,
                                           __half* __restrict__ nt,
                                           int nb, int tid) {
    const int row  = nb * 4 + (tid >> 6);
    const int lane = tid & 63;
    const float4* srow = (const float4*)(s + (size_t)row * DD);
    const float4* trow = (const float4*)(t + (size_t)row * DD);
    float4 vs[3], vt[3];
    float ss = 0.f, tt = 0.f;
#pragma unroll
    for (int i = 0; i < 3; ++i) {
        vs[i] = srow[lane + 64 * i];
        vt[i] = trow[lane + 64 * i];
        ss = fmaf(vs[i].x, vs[i].x, fmaf(vs[i].y, vs[i].y,
             fmaf(vs[i].z, vs[i].z, fmaf(vs[i].w, vs[i].w, ss))));
        tt = fmaf(vt[i].x, vt[i].x, fmaf(vt[i].y, vt[i].y,
             fmaf(vt[i].z, vt[i].z, fmaf(vt[i].w, vt[i].w, tt))));
    }
#pragma unroll
    for (int m = 1; m < 64; m <<= 1) {
        ss += __shfl_xor(ss, m);
        tt += __shfl_xor(tt, m);
    }
    const float is_ = 1.0f / fmaxf(sqrtf(ss), EPS_F);
    const float it_ = 1.0f / fmaxf(sqrtf(tt), EPS_F);

    uint2* nsrow = (uint2*)(ns + (size_t)row * DD);
    uint2* ntrow = (uint2*)(nt + (size_t)row * DD);
#pragma unroll
    for (int i = 0; i < 3; ++i) {
        __half2 a0 = __floats2half2_rn(vs[i].x * is_, vs[i].y * is_);
        __half2 a1 = __floats2half2_rn(vs[i].z * is_, vs[i].w * is_);
        __half2 b0 = __floats2half2_rn(vt[i].x * it_, vt[i].y * it_);
        __half2 b1 = __floats2half2_rn(vt[i].z * it_, vt[i].w * it_);
        uint2 ua; ua.x = __builtin_bit_cast(unsigned int, a0);
        ua.y = __builtin_bit_cast(unsigned int, a1);
        uint2 ub; ub.x = __builtin_bit_cast(unsigned int, b0);
        ub.y = __builtin_bit_cast(unsigned int, b1);
        nsrow[lane + 64 * i] = ua;
        ntrow[lane + 64 * i] = ub;
    }
}

// ---------------------------------------------------------------------------
// Fused kernel: 1 topk block per 2 normh blocks (bid%3), so every CU overlaps
// VALU-latency-bound topk with HBM-bound normh from t=0. LDS 16 KB.
// ---------------------------------------------------------------------------
__global__ __launch_bounds__(256) void fused_prep(const float* __restrict__ centers,
                                                  const float* __restrict__ s,
                                                  const float* __restrict__ t,
                                                  int* __restrict__ idx_out,
                                                  __half* __restrict__ ns,
                                                  __half* __restrict__ nt) {
    __shared__ float4 c4[NN];                 // 16 KB
    const int r3 = blockIdx.x % 3;
    const int q3 = blockIdx.x / 3;
    if (r3 == 0)
        topk_wave_body(centers, idx_out, q3, threadIdx.x, c4);
    else
        normh_body(s, t, ns, nt, q3 * 2 + (r3 - 1), threadIdx.x);
}

// standalone topk for the f32 fallback path
__global__ __launch_bounds__(256) void topk_kernel(const float* __restrict__ centers,
                                                   int* __restrict__ idx_out) {
    __shared__ float4 c4[NN];
    topk_wave_body(centers, idx_out, blockIdx.x, threadIdx.x, c4);
}

// ---------------------------------------------------------------------------
// lossh: gather normalized fp16 rows, dot -> cosines, smooth-L1, per-block
// partial. XCD batch-affinity swizzle. (unchanged from rounds 6-9)
// ---------------------------------------------------------------------------
__global__ __launch_bounds__(256) void lossh_kernel(const __half* __restrict__ ns,
                                                    const __half* __restrict__ nt,
                                                    const int* __restrict__ idx,
                                                    float* __restrict__ part) {
    const int bid  = blockIdx.x;
    const int v    = (bid & 7) * 512 + (bid >> 3);   // bijective, nwg%8==0
    const int wave = threadIdx.x >> 6;
    const int lane = threadIdx.x & 63;
    const int p    = v * 4 + wave;
    const int base = p & ~(NN - 1);

    int q[8];
    {
        const int4* ip = (const int4*)(idx + (size_t)p * KK);
        int4 a = ip[0], c = ip[1];
        q[0] = base + a.x; q[1] = base + a.y; q[2] = base + a.z; q[3] = base + a.w;
        q[4] = base + c.x; q[5] = base + c.y; q[6] = base + c.z; q[7] = base + c.w;
    }

    const uint2* srow = (const uint2*)(ns + (size_t)p * DD);
    const uint2* trow = (const uint2*)(nt + (size_t)p * DD);
    uint2 sa[3], ta[3];
#pragma unroll
    for (int c = 0; c < 3; ++c) {
        sa[c] = srow[lane + 64 * c];
        ta[c] = trow[lane + 64 * c];
    }

    uint2 sv[8][3], tv[8][3];
#pragma unroll
    for (int j = 0; j < 8; ++j) {
        const uint2* snb = (const uint2*)(ns + (size_t)q[j] * DD);
        const uint2* tnb = (const uint2*)(nt + (size_t)q[j] * DD);
#pragma unroll
        for (int c = 0; c < 3; ++c) {
            sv[j][c] = snb[lane + 64 * c];
            tv[j][c] = tnb[lane + 64 * c];
        }
    }

    float ds[8], dt[8];
#pragma unroll
    for (int j = 0; j < 8; ++j) {
        float a = 0.f, b = 0.f;
#pragma unroll
        for (int c = 0; c < 3; ++c) {
            a = dot4acc(sa[c], sv[j][c], a);
            b = dot4acc(ta[c], tv[j][c], b);
        }
        ds[j] = a;
        dt[j] = b;
    }
#pragma unroll
    for (int m = 1; m < 64; m <<= 1) {
#pragma unroll
        for (int j = 0; j < 8; ++j) {
            ds[j] += __shfl_xor(ds[j], m);
            dt[j] += __shfl_xor(dt[j], m);
        }
    }
    float sum = 0.f;
#pragma unroll
    for (int j = 0; j < 8; ++j) {
        const float diff = fabsf(ds[j] - dt[j]);     // rows pre-normalized
        sum += diff < BETA_F ? (0.5f * diff * diff / BETA_F) : (diff - 0.5f * BETA_F);
    }

    __shared__ float wpart[4];
    if (lane == 0) wpart[wave] = sum;
    __syncthreads();
    if (threadIdx.x == 0)
        part[v] = (wpart[0] + wpart[1]) + (wpart[2] + wpart[3]);
}

// ---------------------------------------------------------------------------
// f32 fallback path (only if ws_size too small for fp16 copies).
// ---------------------------------------------------------------------------
__global__ __launch_bounds__(256) void norm_kernel(const float* __restrict__ s,
                                                   const float* __restrict__ t,
                                                   float* __restrict__ inv_s,
                                                   float* __restrict__ inv_t) {
    const int row  = blockIdx.x * 4 + (threadIdx.x >> 6);
    const int lane = threadIdx.x & 63;
    const float4* srow = (const float4*)(s + (size_t)row * DD);
    const float4* trow = (const float4*)(t + (size_t)row * DD);
    float ss = 0.f, tt = 0.f;
#pragma unroll
    for (int i = 0; i < 3; ++i) {
        float4 v = srow[lane + 64 * i];
        ss = fmaf(v.x, v.x, fmaf(v.y, v.y, fmaf(v.z, v.z, fmaf(v.w, v.w, ss))));
        float4 w = trow[lane + 64 * i];
        tt = fmaf(w.x, w.x, fmaf(w.y, w.y, fmaf(w.z, w.z, fmaf(w.w, w.w, tt))));
    }
#pragma unroll
    for (int m = 1; m < 64; m <<= 1) {
        ss += __shfl_xor(ss, m);
        tt += __shfl_xor(tt, m);
    }
    if (lane == 0) {
        inv_s[row] = 1.0f / fmaxf(sqrtf(ss), EPS_F);
        inv_t[row] = 1.0f / fmaxf(sqrtf(tt), EPS_F);
    }
}

__global__ __launch_bounds__(256) void lossf_kernel(const float* __restrict__ s,
                                                    const float* __restrict__ t,
                                                    const int* __restrict__ idx,
                                                    const float* __restrict__ inv_s,
                                                    const float* __restrict__ inv_t,
                                                    float* __restrict__ part) {
    const int wave = threadIdx.x >> 6;
    const int lane = threadIdx.x & 63;
    const int p    = blockIdx.x * 4 + wave;
    const int base = p & ~(NN - 1);
    int q[8];
    {
        const int4* ip = (const int4*)(idx + (size_t)p * KK);
        int4 a = ip[0], c = ip[1];
        q[0] = base + a.x; q[1] = base + a.y; q[2] = base + a.z; q[3] = base + a.w;
        q[4] = base + c.x; q[5] = base + c.y; q[6] = base + c.z; q[7] = base + c.w;
    }
    float isq[8], itq[8];
#pragma unroll
    for (int j = 0; j < 8; ++j) { isq[j] = inv_s[q[j]]; itq[j] = inv_t[q[j]]; }
    const float isn = inv_s[p];
    const float itn = inv_t[p];
    const float4* srow = (const float4*)(s + (size_t)p * DD);
    const float4* trow = (const float4*)(t + (size_t)p * DD);
    float4 as0 = srow[lane], as1 = srow[lane + 64], as2 = srow[lane + 128];
    float4 at0 = trow[lane], at1 = trow[lane + 64], at2 = trow[lane + 128];
    float ds[8], dt[8];
#pragma unroll
    for (int j = 0; j < 8; ++j) {
        const float4* snb = (const float4*)(s + (size_t)q[j] * DD);
        const float4* tnb = (const float4*)(t + (size_t)q[j] * DD);
        float4 v0 = snb[lane], v1 = snb[lane + 64], v2 = snb[lane + 128];
        float4 w0 = tnb[lane], w1 = tnb[lane + 64], w2 = tnb[lane + 128];
        float a = 0.f, b = 0.f;
        a = fmaf(as0.x, v0.x, a); a = fmaf(as0.y, v0.y, a);
        a = fmaf(as0.z, v0.z, a); a = fmaf(as0.w, v0.w, a);
        a = fmaf(as1.x, v1.x, a); a = fmaf(as1.y, v1.y, a);
        a = fmaf(as1.z, v1.z, a); a = fmaf(as1.w, v1.w, a);
        a = fmaf(as2.x, v2.x, a); a = fmaf(as2.y, v2.y, a);
        a = fmaf(as2.z, v2.z, a); a = fmaf(as2.w, v2.w, a);
        b = fmaf(at0.x, w0.x, b); b = fmaf(at0.y, w0.y, b);
        b = fmaf(at0.z, w0.z, b); b = fmaf(at0.w, w0.w, b);
        b = fmaf(at1.x, w1.x, b); b = fmaf(at1.y, w1.y, b);
        b = fmaf(at1.z, w1.z, b); b = fmaf(at1.w, w1.w, b);
        b = fmaf(at2.x, w2.x, b); b = fmaf(at2.y, w2.y, b);
        b = fmaf(at2.z, w2.z, b); b = fmaf(at2.w, w2.w, b);
        ds[j] = a; dt[j] = b;
    }
#pragma unroll
    for (int m = 1; m < 64; m <<= 1) {
#pragma unroll
        for (int j = 0; j < 8; ++j) {
            ds[j] += __shfl_xor(ds[j], m);
            dt[j] += __shfl_xor(dt[j], m);
        }
    }
    float sum = 0.f;
#pragma unroll
    for (int j = 0; j < 8; ++j) {
        const float cs   = ds[j] * isn * isq[j];
        const float ct   = dt[j] * itn * itq[j];
        const float diff = fabsf(cs - ct);
        sum += diff < BETA_F ? (0.5f * diff * diff / BETA_F) : (diff - 0.5f * BETA_F);
    }
    __shared__ float wpart[4];
    if (lane == 0) wpart[wave] = sum;
    __syncthreads();
    if (threadIdx.x == 0)
        part[blockIdx.x] = (wpart[0] + wpart[1]) + (wpart[2] + wpart[3]);
}

// ---------------------------------------------------------------------------
// finalize: deterministic tree reduce of 4096 block partials + final scale.
// ---------------------------------------------------------------------------
__global__ __launch_bounds__(256) void finalize_kernel(const float* __restrict__ part,
                                                       float* __restrict__ out) {
    __shared__ float red[256];
    float acc = 0.f;
    for (int i = threadIdx.x; i < (BB * NN) / 4; i += 256) acc += part[i];
    red[threadIdx.x] = acc;
    __syncthreads();
    for (int off = 128; off > 0; off >>= 1) {
        if (threadIdx.x < off) red[threadIdx.x] += red[threadIdx.x + off];
        __syncthreads();
    }
    if (threadIdx.x == 0) out[0] = red[0] * (1.0f / (float)(BB * NN * KK));
}

extern "C" void kernel_launch(void* const* d_in, const int* in_sizes, int n_in,
                              void* d_out, int out_size, void* d_ws, size_t ws_size,
                              hipStream_t stream) {
    const float* student = (const float*)d_in[0];
    const float* teacher = (const float*)d_in[1];
    const float* centers = (const float*)d_in[2];
    float* out = (float*)d_out;

    const size_t idx_bytes  = (size_t)BB * NN * KK * sizeof(int);      // 512 KB
    const size_t half_bytes = (size_t)BB * NN * DD * sizeof(__half);   // 25.2 MB
    const size_t part_bytes = 4096 * sizeof(float);
    int* idx_buf = (int*)d_ws;

    if (ws_size >= idx_bytes + 2 * half_bytes + part_bytes) {
        __half* ns  = (__half*)((char*)d_ws + idx_bytes);
        __half* nt  = ns + (size_t)BB * NN * DD;
        float* part = (float*)((char*)d_ws + idx_bytes + 2 * half_bytes);
        fused_prep<<<TPK_BLOCKS + NORM_BLOCKS, 256, 0, stream>>>(centers, student,
                                                                 teacher, idx_buf, ns, nt);
        lossh_kernel<<<NORM_BLOCKS, 256, 0, stream>>>(ns, nt, idx_buf, part);
        finalize_kernel<<<1, 256, 0, stream>>>(part, out);
    } else {
        float* inv_s = (float*)((char*)d_ws + idx_bytes);
        float* inv_t = inv_s + BB * NN;
        float* part  = inv_t + BB * NN;
        topk_kernel<<<TPK_BLOCKS, 256, 0, stream>>>(centers, idx_buf);
        norm_kernel<<<NORM_BLOCKS, 256, 0, stream>>>(student, teacher, inv_s, inv_t);
        lossf_kernel<<<NORM_BLOCKS, 256, 0, stream>>>(student, teacher, idx_buf,
                                                      inv_s, inv_t, part);
        finalize_kernel<<<1, 256, 0, stream>>>(part, out);
    }
}

// Round 11
// 81.947 us; speedup vs baseline: 1.1438x; 1.0331x over previous
//
#include <hip/hip_runtime.h>
#include <hip/hip_fp16.h>
#include <math.h>

#define BB 16
#define NN 1024
#define DD 768
#define KK 8
#define BETA_F 0.5f
#define EPS_F 1e-8f

#define TPK_BLOCKS ((BB * NN) / 8)         // 2048: 4 waves/block x 2 points/wave
#define NORM_BLOCKS ((BB * NN) / 4)        // 4096

typedef _Float16 h2_t __attribute__((ext_vector_type(2)));

#if defined(__has_builtin)
#if __has_builtin(__builtin_amdgcn_fdot2)
#define HAVE_FDOT2 1
#endif
#endif

// acc += dot of 4 halves packed in uint2 (v_dot2_f32_f16 x2, or unpack-fma fallback)
__device__ __forceinline__ float dot4acc(uint2 a, uint2 b, float acc) {
#ifdef HAVE_FDOT2
    acc = __builtin_amdgcn_fdot2(__builtin_bit_cast(h2_t, a.x),
                                 __builtin_bit_cast(h2_t, b.x), acc, false);
    acc = __builtin_amdgcn_fdot2(__builtin_bit_cast(h2_t, a.y),
                                 __builtin_bit_cast(h2_t, b.y), acc, false);
#else
    float2 fa = __half22float2(__builtin_bit_cast(__half2, a.x));
    float2 fb = __half22float2(__builtin_bit_cast(__half2, b.x));
    acc = fmaf(fa.x, fb.x, acc); acc = fmaf(fa.y, fb.y, acc);
    fa = __half22float2(__builtin_bit_cast(__half2, a.y));
    fb = __half22float2(__builtin_bit_cast(__half2, b.y));
    acc = fmaf(fa.x, fb.x, acc); acc = fmaf(fa.y, fb.y, acc);
#endif
    return acc;
}

// ---------------------------------------------------------------------------
// Wave-wide u32 min via DPP (VALU pipe, 1-cyc-issue v_min_u32). Same control
// sequence as the r9/r10 f64 version (proven bit-exact); min is
// order-independent. Lane 63 holds the min after 6 steps; readlane broadcasts.
// ---------------------------------------------------------------------------
__device__ __forceinline__ unsigned wave_min_u32_to_all(unsigned x) {
    int v = (int)x;
#define STEP(CTRL, RM) {                                                    \
        int y_ = __builtin_amdgcn_update_dpp(v, v, CTRL, RM, 0xf, false);   \
        v = (int)((unsigned)v < (unsigned)y_ ? (unsigned)v : (unsigned)y_); \
    }
    STEP(0x111, 0xf)   // row_shr:1
    STEP(0x112, 0xf)   // row_shr:2
    STEP(0x114, 0xf)   // row_shr:4
    STEP(0x118, 0xf)   // row_shr:8
    STEP(0x142, 0xa)   // row_bcast:15 -> rows 1,3
    STEP(0x143, 0xc)   // row_bcast:31 -> rows 2,3
#undef STEP
    return (unsigned)__builtin_amdgcn_readlane(v, 63);
}

// ---------------------------------------------------------------------------
// topk: exact top-9 NN, wave-wide 9-round min extraction, TWO-PHASE u32:
//   phase 1: g = wave-min of u (monotone-uint32 of d2, unchanged arithmetic)
//   phase 2: winning m = min{ i*64+lane : k[i]==g } via 16x ballot + SALU
//            descending-i cselect/ctz chain (scalar pipe, co-issues free).
// Lexicographic (u, m) min == the proven f64 key u*1024+m -> selection is
// bit-identical to rounds 6-10 (absmax 0.0). Kill + tree rebuild now u32.
// Two independent points per wave (r10's ILP win kept).
// ---------------------------------------------------------------------------
__device__ __forceinline__ unsigned topk_u(float anx, float any_, float sqn, float4 c) {
    float dot = anx * c.x + any_ * c.y;
    float d2  = (sqn + c.z) - 2.0f * dot;
    unsigned int u = __float_as_uint(d2);
    u ^= (unsigned int)((int)u >> 31) | 0x80000000u;
    return u;
}

struct KeysU { unsigned k[16]; };

// zero-cost: force the 16 key u32s into arch VGPRs (blocks AGPR/scratch demotion)
#define PIN_KEYSU(K)                                                        \
    asm("" : "+v"(K.k[0]),  "+v"(K.k[1]),  "+v"(K.k[2]),  "+v"(K.k[3]),    \
             "+v"(K.k[4]),  "+v"(K.k[5]),  "+v"(K.k[6]),  "+v"(K.k[7]),    \
             "+v"(K.k[8]),  "+v"(K.k[9]),  "+v"(K.k[10]), "+v"(K.k[11]),   \
             "+v"(K.k[12]), "+v"(K.k[13]), "+v"(K.k[14]), "+v"(K.k[15]))

__device__ __forceinline__ void initkeysu(KeysU& K, float anx, float any_, float sqn,
                                          const float4* c4, int lane) {
#pragma unroll
    for (int i = 0; i < 16; ++i) {
        const int m_ = i * 64 + lane;
        K.k[i] = topk_u(anx, any_, sqn, c4[m_]);
    }
}

__device__ __forceinline__ unsigned umin2(unsigned a, unsigned b) { return a < b ? a : b; }

__device__ __forceinline__ unsigned mintreeu(const KeysU& K) {
    return umin2(umin2(umin2(umin2(K.k[0], K.k[1]),  umin2(K.k[2], K.k[3])),
                       umin2(umin2(K.k[4], K.k[5]),  umin2(K.k[6], K.k[7]))),
                 umin2(umin2(umin2(K.k[8], K.k[9]),  umin2(K.k[10], K.k[11])),
                       umin2(umin2(K.k[12], K.k[13]), umin2(K.k[14], K.k[15]))));
}

__device__ __forceinline__ void topk_wave_body(const float* __restrict__ centers,
                                               int* __restrict__ idx_out,
                                               int tb, int tid, float4* c4) {
    const int b    = tb >> 7;          // 128 topk blocks per batch
    const int grp  = tb & 127;
    const int wave = tid >> 6;
    const int lane = tid & 63;

    // stage packed (x, y, x^2+y^2) — identical arithmetic to prior rounds
    const float4* cbase = (const float4*)(centers + (size_t)b * NN * 2);
    for (int i = tid; i < NN / 2; i += 256) {
        float4 v = cbase[i];
        c4[2 * i + 0] = make_float4(v.x, v.y, v.x * v.x + v.y * v.y, 0.f);
        c4[2 * i + 1] = make_float4(v.z, v.w, v.z * v.z + v.w * v.w, 0.f);
    }
    __syncthreads();

    const int nA = grp * 8 + wave * 2;   // two points per wave
    const int nB = nA + 1;
    const float4 cA = c4[nA];
    const float4 cB = c4[nB];

    KeysU KA, KB;
    initkeysu(KA, cA.x, cA.y, cA.z, c4, lane);
    initkeysu(KB, cB.x, cB.y, cB.z, c4, lane);
    PIN_KEYSU(KA);
    PIN_KEYSU(KB);

    unsigned lmA = mintreeu(KA);
    unsigned lmB = mintreeu(KB);
    int mmA[9], mmB[9];

#pragma unroll
    for (int r = 0; r < 9; ++r) {
        const unsigned gA = wave_min_u32_to_all(lmA);
        const unsigned gB = wave_min_u32_to_all(lmB);

        // phase 2: min m among keys equal to g (ballot -> SALU chain)
        unsigned mA = 0xffffffffu, mB = 0xffffffffu;
#pragma unroll
        for (int i = 15; i >= 0; --i) {
            unsigned long long bA = __ballot(KA.k[i] == gA);
            unsigned long long bB = __ballot(KB.k[i] == gB);
            mA = bA ? (unsigned)(i * 64) + (unsigned)__builtin_ctzll(bA) : mA;
            mB = bB ? (unsigned)(i * 64) + (unsigned)__builtin_ctzll(bB) : mB;
        }
        mmA[r] = (int)mA;
        mmB[r] = (int)mB;

        // kill exactly the winning (i, lane) key
        const unsigned iwA = mA >> 6, lwA = mA & 63;
        const unsigned iwB = mB >> 6, lwB = mB & 63;
        const bool winA = ((unsigned)lane == lwA);
        const bool winB = ((unsigned)lane == lwB);
#pragma unroll
        for (int i = 0; i < 16; ++i) {
            KA.k[i] = ((unsigned)i == iwA && winA) ? 0xffffffffu : KA.k[i];
            KB.k[i] = ((unsigned)i == iwB && winB) ? 0xffffffffu : KB.k[i];
        }
        PIN_KEYSU(KA);
        PIN_KEYSU(KB);
        lmA = mintreeu(KA);
        lmB = mintreeu(KB);
    }

    if (lane == 0) {
        int* outp = idx_out + ((size_t)b * NN + nA) * KK;   // nB rows follow
        ((int4*)outp)[0] = make_int4(mmA[1], mmA[2], mmA[3], mmA[4]);
        ((int4*)outp)[1] = make_int4(mmA[5], mmA[6], mmA[7], mmA[8]);
        ((int4*)outp)[2] = make_int4(mmB[1], mmB[2], mmB[3], mmB[4]);
        ((int4*)outp)[3] = make_int4(mmB[5], mmB[6], mmB[7], mmB[8]);
    }
}

// ---------------------------------------------------------------------------
// normh body: row-normalize s,t in fp32, emit normalized fp16. One wave/row.
// (unchanged from rounds 6-10)
// ---------------------------------------------------------------------------
__device__ __forceinline__ void normh_body(const float* __restrict__ s,
                                           const float* __restrict__ t,
                                           __half* __restrict__ ns,
                                           __half* __restrict__ nt,
                                           int nb, int tid) {
    const int row  = nb * 4 + (tid >> 6);
    const int lane = tid & 63;
    const float4* srow = (const float4*)(s + (size_t)row * DD);
    const float4* trow = (const float4*)(t + (size_t)row * DD);
    float4 vs[3], vt[3];
    float ss = 0.f, tt = 0.f;
#pragma unroll
    for (int i = 0; i < 3; ++i) {
        vs[i] = srow[lane + 64 * i];
        vt[i] = trow[lane + 64 * i];
        ss = fmaf(vs[i].x, vs[i].x, fmaf(vs[i].y, vs[i].y,
             fmaf(vs[i].z, vs[i].z, fmaf(vs[i].w, vs[i].w, ss))));
        tt = fmaf(vt[i].x, vt[i].x, fmaf(vt[i].y, vt[i].y,
             fmaf(vt[i].z, vt[i].z, fmaf(vt[i].w, vt[i].w, tt))));
    }
#pragma unroll
    for (int m = 1; m < 64; m <<= 1) {
        ss += __shfl_xor(ss, m);
        tt += __shfl_xor(tt, m);
    }
    const float is_ = 1.0f / fmaxf(sqrtf(ss), EPS_F);
    const float it_ = 1.0f / fmaxf(sqrtf(tt), EPS_F);

    uint2* nsrow = (uint2*)(ns + (size_t)row * DD);
    uint2* ntrow = (uint2*)(nt + (size_t)row * DD);
#pragma unroll
    for (int i = 0; i < 3; ++i) {
        __half2 a0 = __floats2half2_rn(vs[i].x * is_, vs[i].y * is_);
        __half2 a1 = __floats2half2_rn(vs[i].z * is_, vs[i].w * is_);
        __half2 b0 = __floats2half2_rn(vt[i].x * it_, vt[i].y * it_);
        __half2 b1 = __floats2half2_rn(vt[i].z * it_, vt[i].w * it_);
        uint2 ua; ua.x = __builtin_bit_cast(unsigned int, a0);
        ua.y = __builtin_bit_cast(unsigned int, a1);
        uint2 ub; ub.x = __builtin_bit_cast(unsigned int, b0);
        ub.y = __builtin_bit_cast(unsigned int, b1);
        nsrow[lane + 64 * i] = ua;
        ntrow[lane + 64 * i] = ub;
    }
}

// ---------------------------------------------------------------------------
// Fused kernel: 1 topk block per 2 normh blocks (bid%3), so every CU overlaps
// VALU-bound topk with HBM-bound normh from t=0. LDS 16 KB.
// ---------------------------------------------------------------------------
__global__ __launch_bounds__(256) void fused_prep(const float* __restrict__ centers,
                                                  const float* __restrict__ s,
                                                  const float* __restrict__ t,
                                                  int* __restrict__ idx_out,
                                                  __half* __restrict__ ns,
                                                  __half* __restrict__ nt) {
    __shared__ float4 c4[NN];                 // 16 KB
    const int r3 = blockIdx.x % 3;
    const int q3 = blockIdx.x / 3;
    if (r3 == 0)
        topk_wave_body(centers, idx_out, q3, threadIdx.x, c4);
    else
        normh_body(s, t, ns, nt, q3 * 2 + (r3 - 1), threadIdx.x);
}

// standalone topk for the f32 fallback path
__global__ __launch_bounds__(256) void topk_kernel(const float* __restrict__ centers,
                                                   int* __restrict__ idx_out) {
    __shared__ float4 c4[NN];
    topk_wave_body(centers, idx_out, blockIdx.x, threadIdx.x, c4);
}

// ---------------------------------------------------------------------------
// lossh: gather normalized fp16 rows, dot -> cosines, smooth-L1, per-block
// partial. XCD batch-affinity swizzle. (unchanged from rounds 6-10)
// ---------------------------------------------------------------------------
__global__ __launch_bounds__(256) void lossh_kernel(const __half* __restrict__ ns,
                                                    const __half* __restrict__ nt,
                                                    const int* __restrict__ idx,
                                                    float* __restrict__ part) {
    const int bid  = blockIdx.x;
    const int v    = (bid & 7) * 512 + (bid >> 3);   // bijective, nwg%8==0
    const int wave = threadIdx.x >> 6;
    const int lane = threadIdx.x & 63;
    const int p    = v * 4 + wave;
    const int base = p & ~(NN - 1);

    int q[8];
    {
        const int4* ip = (const int4*)(idx + (size_t)p * KK);
        int4 a = ip[0], c = ip[1];
        q[0] = base + a.x; q[1] = base + a.y; q[2] = base + a.z; q[3] = base + a.w;
        q[4] = base + c.x; q[5] = base + c.y; q[6] = base + c.z; q[7] = base + c.w;
    }

    const uint2* srow = (const uint2*)(ns + (size_t)p * DD);
    const uint2* trow = (const uint2*)(nt + (size_t)p * DD);
    uint2 sa[3], ta[3];
#pragma unroll
    for (int c = 0; c < 3; ++c) {
        sa[c] = srow[lane + 64 * c];
        ta[c] = trow[lane + 64 * c];
    }

    uint2 sv[8][3], tv[8][3];
#pragma unroll
    for (int j = 0; j < 8; ++j) {
        const uint2* snb = (const uint2*)(ns + (size_t)q[j] * DD);
        const uint2* tnb = (const uint2*)(nt + (size_t)q[j] * DD);
#pragma unroll
        for (int c = 0; c < 3; ++c) {
            sv[j][c] = snb[lane + 64 * c];
            tv[j][c] = tnb[lane + 64 * c];
        }
    }

    float ds[8], dt[8];
#pragma unroll
    for (int j = 0; j < 8; ++j) {
        float a = 0.f, b = 0.f;
#pragma unroll
        for (int c = 0; c < 3; ++c) {
            a = dot4acc(sa[c], sv[j][c], a);
            b = dot4acc(ta[c], tv[j][c], b);
        }
        ds[j] = a;
        dt[j] = b;
    }
#pragma unroll
    for (int m = 1; m < 64; m <<= 1) {
#pragma unroll
        for (int j = 0; j < 8; ++j) {
            ds[j] += __shfl_xor(ds[j], m);
            dt[j] += __shfl_xor(dt[j], m);
        }
    }
    float sum = 0.f;
#pragma unroll
    for (int j = 0; j < 8; ++j) {
        const float diff = fabsf(ds[j] - dt[j]);     // rows pre-normalized
        sum += diff < BETA_F ? (0.5f * diff * diff / BETA_F) : (diff - 0.5f * BETA_F);
    }

    __shared__ float wpart[4];
    if (lane == 0) wpart[wave] = sum;
    __syncthreads();
    if (threadIdx.x == 0)
        part[v] = (wpart[0] + wpart[1]) + (wpart[2] + wpart[3]);
}

// ---------------------------------------------------------------------------
// f32 fallback path (only if ws_size too small for fp16 copies).
// ---------------------------------------------------------------------------
__global__ __launch_bounds__(256) void norm_kernel(const float* __restrict__ s,
                                                   const float* __restrict__ t,
                                                   float* __restrict__ inv_s,
                                                   float* __restrict__ inv_t) {
    const int row  = blockIdx.x * 4 + (threadIdx.x >> 6);
    const int lane = threadIdx.x & 63;
    const float4* srow = (const float4*)(s + (size_t)row * DD);
    const float4* trow = (const float4*)(t + (size_t)row * DD);
    float ss = 0.f, tt = 0.f;
#pragma unroll
    for (int i = 0; i < 3; ++i) {
        float4 v = srow[lane + 64 * i];
        ss = fmaf(v.x, v.x, fmaf(v.y, v.y, fmaf(v.z, v.z, fmaf(v.w, v.w, ss))));
        float4 w = trow[lane + 64 * i];
        tt = fmaf(w.x, w.x, fmaf(w.y, w.y, fmaf(w.z, w.z, fmaf(w.w, w.w, tt))));
    }
#pragma unroll
    for (int m = 1; m < 64; m <<= 1) {
        ss += __shfl_xor(ss, m);
        tt += __shfl_xor(tt, m);
    }
    if (lane == 0) {
        inv_s[row] = 1.0f / fmaxf(sqrtf(ss), EPS_F);
        inv_t[row] = 1.0f / fmaxf(sqrtf(tt), EPS_F);
    }
}

__global__ __launch_bounds__(256) void lossf_kernel(const float* __restrict__ s,
                                                    const float* __restrict__ t,
                                                    const int* __restrict__ idx,
                                                    const float* __restrict__ inv_s,
                                                    const float* __restrict__ inv_t,
                                                    float* __restrict__ part) {
    const int wave = threadIdx.x >> 6;
    const int lane = threadIdx.x & 63;
    const int p    = blockIdx.x * 4 + wave;
    const int base = p & ~(NN - 1);
    int q[8];
    {
        const int4* ip = (const int4*)(idx + (size_t)p * KK);
        int4 a = ip[0], c = ip[1];
        q[0] = base + a.x; q[1] = base + a.y; q[2] = base + a.z; q[3] = base + a.w;
        q[4] = base + c.x; q[5] = base + c.y; q[6] = base + c.z; q[7] = base + c.w;
    }
    float isq[8], itq[8];
#pragma unroll
    for (int j = 0; j < 8; ++j) { isq[j] = inv_s[q[j]]; itq[j] = inv_t[q[j]]; }
    const float isn = inv_s[p];
    const float itn = inv_t[p];
    const float4* srow = (const float4*)(s + (size_t)p * DD);
    const float4* trow = (const float4*)(t + (size_t)p * DD);
    float4 as0 = srow[lane], as1 = srow[lane + 64], as2 = srow[lane + 128];
    float4 at0 = trow[lane], at1 = trow[lane + 64], at2 = trow[lane + 128];
    float ds[8], dt[8];
#pragma unroll
    for (int j = 0; j < 8; ++j) {
        const float4* snb = (const float4*)(s + (size_t)q[j] * DD);
        const float4* tnb = (const float4*)(t + (size_t)q[j] * DD);
        float4 v0 = snb[lane], v1 = snb[lane + 64], v2 = snb[lane + 128];
        float4 w0 = tnb[lane], w1 = tnb[lane + 64], w2 = tnb[lane + 128];
        float a = 0.f, b = 0.f;
        a = fmaf(as0.x, v0.x, a); a = fmaf(as0.y, v0.y, a);
        a = fmaf(as0.z, v0.z, a); a = fmaf(as0.w, v0.w, a);
        a = fmaf(as1.x, v1.x, a); a = fmaf(as1.y, v1.y, a);
        a = fmaf(as1.z, v1.z, a); a = fmaf(as1.w, v1.w, a);
        a = fmaf(as2.x, v2.x, a); a = fmaf(as2.y, v2.y, a);
        a = fmaf(as2.z, v2.z, a); a = fmaf(as2.w, v2.w, a);
        b = fmaf(at0.x, w0.x, b); b = fmaf(at0.y, w0.y, b);
        b = fmaf(at0.z, w0.z, b); b = fmaf(at0.w, w0.w, b);
        b = fmaf(at1.x, w1.x, b); b = fmaf(at1.y, w1.y, b);
        b = fmaf(at1.z, w1.z, b); b = fmaf(at1.w, w1.w, b);
        b = fmaf(at2.x, w2.x, b); b = fmaf(at2.y, w2.y, b);
        b = fmaf(at2.z, w2.z, b); b = fmaf(at2.w, w2.w, b);
        ds[j] = a; dt[j] = b;
    }
#pragma unroll
    for (int m = 1; m < 64; m <<= 1) {
#pragma unroll
        for (int j = 0; j < 8; ++j) {
            ds[j] += __shfl_xor(ds[j], m);
            dt[j] += __shfl_xor(dt[j], m);
        }
    }
    float sum = 0.f;
#pragma unroll
    for (int j = 0; j < 8; ++j) {
        const float cs   = ds[j] * isn * isq[j];
        const float ct   = dt[j] * itn * itq[j];
        const float diff = fabsf(cs - ct);
        sum += diff < BETA_F ? (0.5f * diff * diff / BETA_F) : (diff - 0.5f * BETA_F);
    }
    __shared__ float wpart[4];
    if (lane == 0) wpart[wave] = sum;
    __syncthreads();
    if (threadIdx.x == 0)
        part[blockIdx.x] = (wpart[0] + wpart[1]) + (wpart[2] + wpart[3]);
}

// ---------------------------------------------------------------------------
// finalize: deterministic tree reduce of 4096 block partials + final scale.
// ---------------------------------------------------------------------------
__global__ __launch_bounds__(256) void finalize_kernel(const float* __restrict__ part,
                                                       float* __restrict__ out) {
    __shared__ float red[256];
    float acc = 0.f;
    for (int i = threadIdx.x; i < (BB * NN) / 4; i += 256) acc += part[i];
    red[threadIdx.x] = acc;
    __syncthreads();
    for (int off = 128; off > 0; off >>= 1) {
        if (threadIdx.x < off) red[threadIdx.x] += red[threadIdx.x + off];
        __syncthreads();
    }
    if (threadIdx.x == 0) out[0] = red[0] * (1.0f / (float)(BB * NN * KK));
}

extern "C" void kernel_launch(void* const* d_in, const int* in_sizes, int n_in,
                              void* d_out, int out_size, void* d_ws, size_t ws_size,
                              hipStream_t stream) {
    const float* student = (const float*)d_in[0];
    const float* teacher = (const float*)d_in[1];
    const float* centers = (const float*)d_in[2];
    float* out = (float*)d_out;

    const size_t idx_bytes  = (size_t)BB * NN * KK * sizeof(int);      // 512 KB
    const size_t half_bytes = (size_t)BB * NN * DD * sizeof(__half);   // 25.2 MB
    const size_t part_bytes = 4096 * sizeof(float);
    int* idx_buf = (int*)d_ws;

    if (ws_size >= idx_bytes + 2 * half_bytes + part_bytes) {
        __half* ns  = (__half*)((char*)d_ws + idx_bytes);
        __half* nt  = ns + (size_t)BB * NN * DD;
        float* part = (float*)((char*)d_ws + idx_bytes + 2 * half_bytes);
        fused_prep<<<TPK_BLOCKS + NORM_BLOCKS, 256, 0, stream>>>(centers, student,
                                                                 teacher, idx_buf, ns, nt);
        lossh_kernel<<<NORM_BLOCKS, 256, 0, stream>>>(ns, nt, idx_buf, part);
        finalize_kernel<<<1, 256, 0, stream>>>(part, out);
    } else {
        float* inv_s = (float*)((char*)d_ws + idx_bytes);
        float* inv_t = inv_s + BB * NN;
        float* part  = inv_t + BB * NN;
        topk_kernel<<<TPK_BLOCKS, 256, 0, stream>>>(centers, idx_buf);
        norm_kernel<<<NORM_BLOCKS, 256, 0, stream>>>(student, teacher, inv_s, inv_t);
        lossf_kernel<<<NORM_BLOCKS, 256, 0, stream>>>(student, teacher, idx_buf,
                                                      inv_s, inv_t, part);
        finalize_kernel<<<1, 256, 0, stream>>>(part, out);
    }
}